// Round 13
// baseline (353.693 us; speedup 1.0000x reference)
//
#include <hip/hip_runtime.h>
#include <hip/hip_bf16.h>

typedef unsigned int u32;
typedef unsigned long long u64;
typedef unsigned char u8;

#define B_IMG 8
#define N_ANCH 64512
#define NCLS 80
#define ROW 85
#define CONF_T 0.596f
#define IOU_T 0.45f
#define MAXC 512
#define CELL 200
#define CAP 4096

// small histogram: scores live in (0.596, 1.0) -> (key>>16) in [0x3F18, 0x3F7F]
#define HBKT 128
#define KEYBASE 0x3F18u

// k_score staging: 96 rows/block = 2040 float4, 8 f4/thread (named regs), LDS 32.6 KB
#define SR 96
#define SF4 ((SR * ROW) / 4)                 // 2040
#define TOT_F4 ((size_t)B_IMG * N_ANCH * ROW / 4)   // 10,967,040

#define BLK_PER_IMG (N_ANCH / 256)           // 252, exact

__device__ __forceinline__ float fsub(float a, float b){ return __fsub_rn(a,b); }
__device__ __forceinline__ float fadd(float a, float b){ return __fadd_rn(a,b); }
__device__ __forceinline__ float fmul(float a, float b){ return __fmul_rn(a,b); }

// ---------------- Kernel A: score + argmax-class + histogram ----------------
// R5-R9: k_score is at the platform byte-rate floor (~105-110us, FETCH 85.7MB).
// Argmax over PRODUCTS fmul(cls,obj) with strict > (first-max-wins); half-combine
// ties favor half 0 == jnp.argmax first-occurrence. conf = max(products) is
// bit-identical to fmul(max(cls),obj) by fmul monotonicity.
__global__ __launch_bounds__(256) void k_score(const float* __restrict__ outp,
                                               float* __restrict__ scores,
                                               u8* __restrict__ clsarr,
                                               u32* __restrict__ hist) {
    __shared__ float srows[SR * ROW];        // 32,640 B -> 4 blocks/CU

    int tid = threadIdx.x;
    size_t base = (size_t)blockIdx.x * SF4;  // float4 index of block chunk
    const float4* src = (const float4*)outp;

    size_t a = base + tid;
    const size_t amax = TOT_F4 - 1;          // clamp only affects last block's tail
    float4 t0 = src[(a            < amax) ? (a           ) : amax];
    float4 t1 = src[(a + 256      < amax) ? (a + 256     ) : amax];
    float4 t2 = src[(a + 512      < amax) ? (a + 512     ) : amax];
    float4 t3 = src[(a + 768      < amax) ? (a + 768     ) : amax];
    float4 t4 = src[(a + 1024     < amax) ? (a + 1024    ) : amax];
    float4 t5 = src[(a + 1280     < amax) ? (a + 1280    ) : amax];
    float4 t6 = src[(a + 1536     < amax) ? (a + 1536    ) : amax];
    float4 t7 = src[(a + 1792     < amax) ? (a + 1792    ) : amax];

    float4* dst = (float4*)srows;
    dst[tid        ] = t0;
    dst[tid +  256 ] = t1;
    dst[tid +  512 ] = t2;
    dst[tid +  768 ] = t3;
    dst[tid + 1024 ] = t4;
    dst[tid + 1280 ] = t5;
    dst[tid + 1536 ] = t6;
    if (tid < SF4 - 1792) dst[tid + 1792] = t7;   // slots 1792..2039
    __syncthreads();

    // compute: 2 lanes per row; each half tracks (best, bi) over 40 products
    int r = tid >> 1;          // row within block [0,96) for tid < 192
    int h = tid & 1;           // half: classes [40h, 40h+40)
    float score = -1.0f;
    int cls = 0;
    int gi = blockIdx.x * SR + r;
    if (tid < 192) {           // waves 0..2 fully active -> shfl_xor(1) safe
        const float* row = srows + r * ROW;
        float obj = row[4];
        const float* cp = row + 5 + h * 40;
        float best = -1.0f; int bi = h * 40;
        #pragma unroll
        for (int c = 0; c < 40; ++c) {
            float v = fmul(cp[c], obj);      // products, reference op
            if (v > best) { best = v; bi = h * 40 + c; }
        }
        float ob  = __shfl_xor(best, 1);
        int   obi = __shfl_xor(bi, 1);
        // from h==0's perspective: other is half 1 -> take only if strictly greater
        float conf;
        if (ob > best) { conf = ob; cls = obi; }
        else           { conf = best; cls = bi; }
        score = (conf > CONF_T) ? conf : -1.0f;
    }

    if (tid < 192 && h == 0) {
        scores[gi] = score;
        clsarr[gi] = (u8)cls;
        if (score > 0.0f) {
            int b = gi / N_ANCH;
            u32 bk = (__float_as_uint(score) >> 16) - KEYBASE;
            if (bk > HBKT - 1) bk = HBKT - 1;   // unreachable for (0.596,1) scores; safety
            atomicAdd(&hist[(size_t)b * HBKT + bk], 1u);
        }
    }
}

// ---------------- Kernel C: compact candidates (threshold computed in-block) ----------------
// R13: k_thresh folded in. b is block-uniform (252 blocks per image, exact).
// Each block parallel-loads its image's 128-bucket hist into LDS; lane 0 runs
// the identical suffix scan; all threads filter against the shared threshold.
__global__ __launch_bounds__(256) void k_compact(const float* __restrict__ scores,
                                                 const u32* __restrict__ hist,
                                                 u32* __restrict__ cnt,
                                                 u64* __restrict__ list) {
    __shared__ u32 h[HBKT];
    __shared__ u32 sthresh;
    int b = blockIdx.x / BLK_PER_IMG;
    int tid = threadIdx.x;
    if (tid < HBKT) h[tid] = hist[(size_t)b * HBKT + tid];
    __syncthreads();
    if (tid == 0) {
        u32 c2 = 0;
        int bkt = HBKT - 1;
        for (; bkt >= 0; --bkt) {
            c2 += h[bkt];
            if (c2 >= MAXC) break;
        }
        sthresh = (bkt < 0) ? 0u : (((u32)bkt + KEYBASE) << 16);
    }
    __syncthreads();

    int i = blockIdx.x * 256 + tid;
    float s = scores[i];
    if (s <= 0.0f) return;
    u32 key = __float_as_uint(s);
    if (key < sthresh) return;
    u32 pos = atomicAdd(&cnt[b], 1u);
    if (pos < CAP) {
        u32 n = (u32)(i - b * N_ANCH);
        // descending sort of packed => key desc, index asc on ties (stable argsort match)
        list[(size_t)b * CAP + pos] = ((u64)key << 32) | (u64)(0xFFFFFFFFu - n);
    }
}

// ---------------- Kernel D: fused sort + IoU + greedy NMS + compaction ----------------
// R13: k_sort + k_iou + k_greedy fused into one per-image block. Everything
// stays in LDS (buf reused as sup bitmatrix after the sort, barrier-separated);
// IoU via 36 wave-assigned 64x64 tiles with wave-uniform inner index
// (LDS broadcast reads, no conflicts). Saves 2 launches + 512KB global traffic.
#define GW(W, KW, NE, APPLY) \
    { u64 todo = (KW) & (NE); \
      while (todo) { \
          int bb = (int)__builtin_ctzll(todo); \
          const u64* rr = srow + (((W) * 64 + bb) * 8); \
          u64 hm = (bb < 63) ? (~0ull << (bb + 1)) : 0ull; \
          KW &= ~(rr[W] & hm); \
          APPLY \
          todo &= hm & KW; \
      } }

__global__ __launch_bounds__(512) void k_nms2(const float* __restrict__ outp,
                                              const u8* __restrict__ clsarr,
                                              const u32* __restrict__ cnt,
                                              const u64* __restrict__ list,
                                              float* __restrict__ selbox,
                                              u32* __restrict__ selcnt,
                                              float* __restrict__ mask_out) {
    __shared__ u64 buf[CAP];            // 32 KB: sort buffer, then sup bitmatrix
    __shared__ float4 oboxs[MAXC];      // 8 KB
    __shared__ float  areas[MAXC];      // 2 KB
    __shared__ float4 bxs[MAXC];        // 8 KB
    __shared__ u64 keepw[8];
    __shared__ u64 neword[8];
    int b = blockIdx.x;
    int tid = threadIdx.x;

    // ---- phase 1: load + bitonic sort (descending) ----
    int M = (int)min(cnt[b], (u32)CAP);
    int P = MAXC;
    while (P < M) P <<= 1;

    for (int t = tid; t < P; t += 512)
        buf[t] = (t < M) ? list[(size_t)b * CAP + t] : 0ull;
    __syncthreads();

    for (int k = 2; k <= P; k <<= 1) {
        for (int j = k >> 1; j > 0; j >>= 1) {
            for (int t = tid; t < P; t += 512) {
                int ixj = t ^ j;
                if (ixj > t) {
                    u64 a = buf[t], c = buf[ixj];
                    bool desc = ((t & k) == 0);
                    if (desc ? (a < c) : (a > c)) { buf[t] = c; buf[ixj] = a; }
                }
            }
            __syncthreads();
        }
    }

    int nvalid = min(M, MAXC);
    bool valid = (tid < nvalid);
    u32 n = 0;
    if (valid) n = 0xFFFFFFFFu - (u32)(buf[tid] & 0xFFFFFFFFull);
    __syncthreads();   // all reads of buf done before reuse as sup

    // ---- phase 2: box extraction (reference float ops exactly) ----
    float bx0, bx1, bx2, bx3;
    float ob0, ob1, ob2, ob3;
    if (valid) {
        const float* p = outp + ((size_t)b * N_ANCH + n) * ROW;
        float cx = p[0], cy = p[1], w = p[2], h = p[3];
        int bi = (int)clsarr[(size_t)b * N_ANCH + n];
        float hw = fmul(w, 0.5f), hh = fmul(h, 0.5f);
        bx0 = fsub(cx, hw); bx1 = fsub(cy, hh);
        bx2 = fadd(cx, hw); bx3 = fadd(cy, hh);
        float off = fmul((float)bi, 4096.0f);
        ob0 = fadd(bx0, off); ob1 = fadd(bx1, off);
        ob2 = fadd(bx2, off); ob3 = fadd(bx3, off);
    } else {
        bx0 = bx1 = bx2 = bx3 = 0.0f;
        ob0 = ob1 = ob2 = ob3 = -1.0e6f;  // degenerate far box, iou -> 0
    }
    oboxs[tid] = make_float4(ob0, ob1, ob2, ob3);
    areas[tid] = fmul(fsub(ob2, ob0), fsub(ob3, ob1));
    bxs[tid]   = make_float4(bx0, bx1, bx2, bx3);
    __syncthreads();

    // ---- phase 3: IoU bitmatrix, 36 upper-tri 64x64 tiles over 8 waves ----
    u64* sup = buf;                     // sup[i*8 + w]
    {
        int wave = tid >> 6, lane = tid & 63;
        for (int t = wave; t < 36; t += 8) {
            int tt = t, ti = 0;
            while (tt >= 8 - ti) { tt -= 8 - ti; ++ti; }
            int tj = ti + tt;

            int i = ti * 64 + lane;
            float4 oi = oboxs[i];
            float ai = areas[i];
            u64 bits = 0;
            for (int jl = 0; jl < 64; ++jl) {    // jl wave-uniform -> broadcast reads
                int j = tj * 64 + jl;
                float4 oj = oboxs[j];
                float aj = areas[j];
                float ltx = fmaxf(oi.x, oj.x);
                float lty = fmaxf(oi.y, oj.y);
                float rbx = fminf(oi.z, oj.z);
                float rby = fminf(oi.w, oj.w);
                float ww = fmaxf(fsub(rbx, ltx), 0.0f);
                float hh2 = fmaxf(fsub(rby, lty), 0.0f);
                float inter = fmul(ww, hh2);
                float denom = fadd(fsub(fadd(ai, aj), inter), 1e-9f);
                float iou = __fdiv_rn(inter, denom);
                if ((j > i) && (iou > IOU_T)) bits |= (1ull << jl);
            }
            if (ti == tj) {
                for (int w = 0; w < ti; ++w) sup[(size_t)i * 8 + w] = 0ull;
            }
            sup[(size_t)i * 8 + tj] = bits;
        }
    }
    __syncthreads();

    // ---- phase 4: non-empty-row mask + keep init ----
    {
        u64 r0 = sup[tid*8+0], r1 = sup[tid*8+1], r2 = sup[tid*8+2], r3 = sup[tid*8+3];
        u64 r4 = sup[tid*8+4], r5 = sup[tid*8+5], r6 = sup[tid*8+6], r7 = sup[tid*8+7];
        bool ne = ((r0|r1|r2|r3|r4|r5|r6|r7) != 0ull);
        u64 bal = __ballot(ne);
        if ((tid & 63) == 0) neword[tid >> 6] = bal;
    }
    if (tid < 8) {
        int lo = tid * 64;
        u64 kw = 0;
        if (nvalid >= lo + 64) kw = ~0ull;
        else if (nvalid > lo) kw = (1ull << (nvalid - lo)) - 1ull;
        keepw[tid] = kw;
    }
    __syncthreads();

    // ---- phase 5: sparse greedy scan (single thread, register-resident) ----
    if (tid == 0) {
        const u64* srow = sup;
        u64 k0=keepw[0], k1=keepw[1], k2=keepw[2], k3=keepw[3];
        u64 k4=keepw[4], k5=keepw[5], k6=keepw[6], k7=keepw[7];
        u64 n0=neword[0], n1=neword[1], n2=neword[2], n3=neword[3];
        u64 n4=neword[4], n5=neword[5], n6=neword[6], n7=neword[7];
        GW(0, k0, n0, k1&=~rr[1]; k2&=~rr[2]; k3&=~rr[3]; k4&=~rr[4]; k5&=~rr[5]; k6&=~rr[6]; k7&=~rr[7];)
        GW(1, k1, n1, k2&=~rr[2]; k3&=~rr[3]; k4&=~rr[4]; k5&=~rr[5]; k6&=~rr[6]; k7&=~rr[7];)
        GW(2, k2, n2, k3&=~rr[3]; k4&=~rr[4]; k5&=~rr[5]; k6&=~rr[6]; k7&=~rr[7];)
        GW(3, k3, n3, k4&=~rr[4]; k5&=~rr[5]; k6&=~rr[6]; k7&=~rr[7];)
        GW(4, k4, n4, k5&=~rr[5]; k6&=~rr[6]; k7&=~rr[7];)
        GW(5, k5, n5, k6&=~rr[6]; k7&=~rr[7];)
        GW(6, k6, n6, k7&=~rr[7];)
        GW(7, k7, n7, )
        keepw[0]=k0; keepw[1]=k1; keepw[2]=k2; keepw[3]=k3;
        keepw[4]=k4; keepw[5]=k5; keepw[6]=k6; keepw[7]=k7;
    }
    __syncthreads();

    // ---- phase 6: compact kept in candidate order (stable top-200) ----
    int w = tid >> 6, l = tid & 63;
    bool kept = valid && ((keepw[w] >> l) & 1ull);
    int rank = 0;
    for (int ww = 0; ww < w; ++ww) rank += __popcll(keepw[ww]);
    rank += __popcll(keepw[w] & ((l == 0) ? 0ull : ((1ull << l) - 1ull)));
    if (kept && rank < CELL) {
        float4 bx = bxs[tid];
        float* sb = selbox + ((size_t)b * CELL + rank) * 4;
        sb[0] = bx.x; sb[1] = bx.y; sb[2] = bx.z; sb[3] = bx.w;
        mask_out[b * CELL + rank] = 1.0f;
    }
    if (tid == 0) {
        int tot = 0;
        for (int ww = 0; ww < 8; ++ww) tot += __popcll(keepw[ww]);
        selcnt[b] = (u32)min(tot, CELL);
    }
}

// ---------------- Kernel E1: ROI gather (one thread per channel x sample-point) ----------------
__global__ __launch_bounds__(256) void k_roi_gather(
        const float* __restrict__ x1, const float* __restrict__ x2,
        const float* __restrict__ x3, const float* __restrict__ x4,
        const float* __restrict__ selbox, const u32* __restrict__ selcnt,
        float* __restrict__ rws) {
    int slot = blockIdx.y;
    int b = blockIdx.z;
    if (slot >= (int)selcnt[b]) return;

    int unit = blockIdx.x * 256 + threadIdx.x;   // 0..7679
    int c = unit >> 2;
    int p = unit & 3;

    const float* fb; int Wd; float s; int cl;
    if (c < 128)      { fb = x1 + (size_t)b * 128 * 128 * 128; Wd = 128; s = 0.125f;    cl = c; }
    else if (c < 384) { fb = x2 + (size_t)b * 256 * 64 * 64;   Wd = 64;  s = 0.0625f;   cl = c - 128; }
    else if (c < 896) { fb = x3 + (size_t)b * 512 * 32 * 32;   Wd = 32;  s = 0.03125f;  cl = c - 384; }
    else              { fb = x4 + (size_t)b * 1024 * 16 * 16;  Wd = 16;  s = 0.015625f; cl = c - 896; }

    const float* sb = selbox + ((size_t)b * CELL + slot) * 4;
    float box0 = sb[0], box1 = sb[1], box2 = sb[2], box3 = sb[3];

    float bx1f = box0 * s, by1f = box1 * s;
    float bw = fmaxf(box2 * s - bx1f, 1.0f);
    float bh = fmaxf(box3 * s - by1f, 1.0f);
    float gx = (p & 1)  ? 0.75f : 0.25f;
    float gy = (p >> 1) ? 0.75f : 0.25f;
    float X = bx1f + gx * bw;
    float Y = by1f + gy * bh;
    X = fminf(fmaxf(X, 0.0f), (float)(Wd - 1));
    Y = fminf(fmaxf(Y, 0.0f), (float)(Wd - 1));
    int x0 = (int)floorf(X), y0 = (int)floorf(Y);
    int x1i = min(x0 + 1, Wd - 1), y1i = min(y0 + 1, Wd - 1);
    float wx = X - (float)x0, wy = Y - (float)y0;

    const float* f = fb + (size_t)cl * Wd * Wd;
    float v = f[y0 * Wd + x0]  * ((1.0f - wy) * (1.0f - wx))
            + f[y0 * Wd + x1i] * ((1.0f - wy) * wx)
            + f[y1i * Wd + x0] * (wy * (1.0f - wx))
            + f[y1i * Wd + x1i]* (wy * wx);

    // combine the 4 points in reference order: ((v0+v1)+v2)+v3, then * 0.25
    int lane = threadIdx.x & 63;
    int base = lane & ~3;
    float v0 = __shfl(v, base + 0);
    float v1 = __shfl(v, base + 1);
    float v2 = __shfl(v, base + 2);
    float v3 = __shfl(v, base + 3);
    if (p == 0) {
        rws[((size_t)b * CELL + slot) * 1920 + c] = (((v0 + v1) + v2) + v3) * 0.25f;
    }
}

// ---------------- Kernel E2: 2-layer MLP, 4 slots/block with W1 register reuse ----------------
__global__ __launch_bounds__(256) void k_mlp(
        const float* __restrict__ W1, const float* __restrict__ b1,
        const float* __restrict__ W2, const float* __restrict__ b2,
        const float* __restrict__ selbox, const u32* __restrict__ selcnt,
        const float* __restrict__ rws, float* __restrict__ feats) {
    int slot0 = blockIdx.x * 4;
    int b = blockIdx.y;
    int nsel = (int)selcnt[b];
    if (slot0 >= nsel) return;
    int tid = threadIdx.x;

    __shared__ float psum[4][4][64];   // [slot][part][j]
    __shared__ float h1s[4][64];

    int j = tid & 63, part = tid >> 6;
    const float* r0 = rws + ((size_t)b * CELL + slot0 + 0) * 1920;
    const float* r1 = rws + ((size_t)b * CELL + slot0 + 1) * 1920;
    const float* r2 = rws + ((size_t)b * CELL + slot0 + 2) * 1920;
    const float* r3 = rws + ((size_t)b * CELL + slot0 + 3) * 1920;
    // slots >= nsel read garbage (allocated memory) and are discarded at write.

    {
        float a0 = 0.0f, a1 = 0.0f, a2 = 0.0f, a3 = 0.0f;
        int k0 = part * 480;
        for (int k = k0; k < k0 + 480; ++k) {
            float w = W1[(size_t)k * 64 + j];
            a0 += r0[k] * w;
            a1 += r1[k] * w;
            a2 += r2[k] * w;
            a3 += r3[k] * w;
        }
        psum[0][part][j] = a0;
        psum[1][part][j] = a1;
        psum[2][part][j] = a2;
        psum[3][part][j] = a3;
    }
    __syncthreads();

    int sl = tid >> 6;                 // 4 slots x 64 j across 256 threads
    int slot = slot0 + sl;
    if (slot < nsel) {
        float v = psum[sl][0][j] + psum[sl][1][j] + psum[sl][2][j] + psum[sl][3][j] + b1[j];
        h1s[sl][j] = (v >= 0.0f) ? v : 0.01f * v;
    }
    __syncthreads();

    if (slot < nsel) {
        float acc = b2[j];
        for (int k = 0; k < 64; ++k) acc += h1s[sl][k] * W2[k * 64 + j];
        float v = (acc >= 0.0f) ? acc : 0.01f * acc;
        float* orow = feats + ((size_t)b * CELL + slot) * 68;
        orow[4 + j] = v;
        if (j < 4) {
            const float* sb = selbox + ((size_t)b * CELL + slot) * 4;
            orow[j] = sb[j] * (1.0f / 1024.0f);
        }
    }
}

// ---------------- Fallback: fused ROI align + MLP (used if workspace too small) ----------------
__global__ __launch_bounds__(256) void k_roi_mlp(
        const float* __restrict__ x1, const float* __restrict__ x2,
        const float* __restrict__ x3, const float* __restrict__ x4,
        const float* __restrict__ W1, const float* __restrict__ b1,
        const float* __restrict__ W2, const float* __restrict__ b2,
        const float* __restrict__ selbox, const u32* __restrict__ selcnt,
        float* __restrict__ feats) {
    int slot = blockIdx.x;
    int b = blockIdx.y;
    if (slot >= (int)selcnt[b]) return;
    int tid = threadIdx.x;

    __shared__ float r[1920];
    __shared__ float psum[4][64];
    __shared__ float h1[64];

    const float* sb = selbox + ((size_t)b * CELL + slot) * 4;
    float box0 = sb[0], box1 = sb[1], box2 = sb[2], box3 = sb[3];

    const float* feat[4] = {
        x1 + (size_t)b * 128 * 128 * 128,
        x2 + (size_t)b * 256 * 64 * 64,
        x3 + (size_t)b * 512 * 32 * 32,
        x4 + (size_t)b * 1024 * 16 * 16
    };
    const int   Cs[4]  = {128, 256, 512, 1024};
    const int   Wd_[4] = {128, 64, 32, 16};
    const float Ss[4]  = {0.125f, 0.0625f, 0.03125f, 0.015625f};
    const int   Off[4] = {0, 128, 384, 896};

    for (int lvl = 0; lvl < 4; ++lvl) {
        int Wd = Wd_[lvl], C = Cs[lvl];
        float s = Ss[lvl];
        float bx1f = box0 * s, by1f = box1 * s;
        float bw = fmaxf(box2 * s - bx1f, 1.0f);
        float bh = fmaxf(box3 * s - by1f, 1.0f);
        float xs[2] = { bx1f + 0.25f * bw, bx1f + 0.75f * bw };
        float ys[2] = { by1f + 0.25f * bh, by1f + 0.75f * bh };
        int idx[4][4]; float wt[4][4];
        for (int p = 0; p < 4; ++p) {
            float X = xs[p & 1], Y = ys[p >> 1];
            X = fminf(fmaxf(X, 0.0f), (float)(Wd - 1));
            Y = fminf(fmaxf(Y, 0.0f), (float)(Wd - 1));
            int x0 = (int)floorf(X), y0 = (int)floorf(Y);
            int x1i = min(x0 + 1, Wd - 1), y1i = min(y0 + 1, Wd - 1);
            float wx = X - (float)x0, wy = Y - (float)y0;
            idx[p][0] = y0 * Wd + x0;  idx[p][1] = y0 * Wd + x1i;
            idx[p][2] = y1i * Wd + x0; idx[p][3] = y1i * Wd + x1i;
            wt[p][0] = (1.0f - wy) * (1.0f - wx); wt[p][1] = (1.0f - wy) * wx;
            wt[p][2] = wy * (1.0f - wx);          wt[p][3] = wy * wx;
        }
        const float* fb = feat[lvl];
        int HW = Wd * Wd;
        for (int c = tid; c < C; c += 256) {
            const float* f = fb + (size_t)c * HW;
            float acc = 0.0f;
            for (int p = 0; p < 4; ++p)
                acc += f[idx[p][0]] * wt[p][0] + f[idx[p][1]] * wt[p][1]
                     + f[idx[p][2]] * wt[p][2] + f[idx[p][3]] * wt[p][3];
            r[Off[lvl] + c] = acc * 0.25f;
        }
    }
    __syncthreads();

    int j = tid & 63, part = tid >> 6;
    {
        float acc = 0.0f;
        int k0 = part * 480;
        for (int k = k0; k < k0 + 480; ++k)
            acc += r[k] * W1[(size_t)k * 64 + j];
        psum[part][j] = acc;
    }
    __syncthreads();
    if (tid < 64) {
        float v = psum[0][tid] + psum[1][tid] + psum[2][tid] + psum[3][tid] + b1[tid];
        h1[tid] = (v >= 0.0f) ? v : 0.01f * v;
    }
    __syncthreads();

    float* orow = feats + ((size_t)b * CELL + slot) * 68;
    if (tid < 64) {
        float acc = b2[tid];
        for (int k = 0; k < 64; ++k) acc += h1[k] * W2[k * 64 + tid];
        float v = (acc >= 0.0f) ? acc : 0.01f * acc;
        orow[4 + tid] = v;
    }
    if (tid < 4) {
        float bv = (tid == 0) ? box0 : (tid == 1) ? box1 : (tid == 2) ? box2 : box3;
        orow[tid] = bv * (1.0f / 1024.0f);
    }
}

extern "C" void kernel_launch(void* const* d_in, const int* in_sizes, int n_in,
                              void* d_out, int out_size, void* d_ws, size_t ws_size,
                              hipStream_t stream) {
    const float* outp = (const float*)d_in[0];
    const float* x1 = (const float*)d_in[1];
    const float* x2 = (const float*)d_in[2];
    const float* x3 = (const float*)d_in[3];
    const float* x4 = (const float*)d_in[4];
    const float* W1 = (const float*)d_in[5];
    const float* b1 = (const float*)d_in[6];
    const float* W2 = (const float*)d_in[7];
    const float* b2 = (const float*)d_in[8];

    char* ws = (char*)d_ws;
    const size_t o_cnt    = 0;                       // 256
    const size_t o_hist   = 256;                     // 8*128*4 = 4096
    const size_t o_scores = 4608;                    // 2,064,384
    const size_t o_cls    = o_scores + 2064384;      // 516,096 (u8 per anchor)
    const size_t o_list   = o_cls + 516096;          // 262,144 (8B aligned)
    const size_t o_selbox = o_list + 262144;         // 25,600
    const size_t o_selcnt = o_selbox + 25600;        // 256
    const size_t o_rws    = o_selcnt + 256;          // 12,288,000
    const size_t ws_need_rws = o_rws + (size_t)B_IMG * CELL * 1920 * 4;

    u32*   cnt    = (u32*)(ws + o_cnt);
    u32*   hist   = (u32*)(ws + o_hist);
    float* scores = (float*)(ws + o_scores);
    u8*    clsarr = (u8*)(ws + o_cls);
    u64*   list   = (u64*)(ws + o_list);
    float* selbox = (float*)(ws + o_selbox);
    u32*   selcnt = (u32*)(ws + o_selcnt);
    float* rws    = (float*)(ws + o_rws);

    float* feats = (float*)d_out;
    float* mask  = feats + (size_t)B_IMG * CELL * 68;

    // zero output (masked rows must be exact 0) and cnt+hist (4.3 KB)
    hipMemsetAsync(d_out, 0, (size_t)out_size * sizeof(float), stream);
    hipMemsetAsync(ws, 0, 4608, stream);

    int total = B_IMG * N_ANCH;
    int blocks = total / 256;                        // 2016, exact
    int score_blocks = total / SR;                   // 5376, exact
    k_score  <<<score_blocks, 256, 0, stream>>>(outp, scores, clsarr, hist);
    k_compact<<<blocks, 256, 0, stream>>>(scores, hist, cnt, list);
    k_nms2   <<<B_IMG, 512, 0, stream>>>(outp, clsarr, cnt, list, selbox, selcnt, mask);

    if (ws_size >= ws_need_rws) {
        k_roi_gather<<<dim3(30, CELL, B_IMG), 256, 0, stream>>>(
            x1, x2, x3, x4, selbox, selcnt, rws);
        k_mlp<<<dim3((CELL + 3) / 4, B_IMG), 256, 0, stream>>>(
            W1, b1, W2, b2, selbox, selcnt, rws, feats);
    } else {
        k_roi_mlp<<<dim3(CELL, B_IMG), 256, 0, stream>>>(
            x1, x2, x3, x4, W1, b1, W2, b2, selbox, selcnt, feats);
    }
}

// Round 14
// 342.688 us; speedup vs baseline: 1.0321x; 1.0321x over previous
//
#include <hip/hip_runtime.h>
#include <hip/hip_bf16.h>

typedef unsigned int u32;
typedef unsigned long long u64;
typedef unsigned char u8;

#define B_IMG 8
#define N_ANCH 64512
#define NCLS 80
#define ROW 85
#define CONF_T 0.596f
#define IOU_T 0.45f
#define MAXC 512
#define CELL 200
#define CAP 4096

// small histogram: scores live in (0.596, 1.0) -> (key>>16) in [0x3F18, 0x3F7F]
#define HBKT 128
#define KEYBASE 0x3F18u

// k_score staging: 96 rows/block = 2040 float4, 8 f4/thread (named regs), LDS 32.6 KB
#define SR 96
#define SF4 ((SR * ROW) / 4)                 // 2040
#define TOT_F4 ((size_t)B_IMG * N_ANCH * ROW / 4)   // 10,967,040

__device__ __forceinline__ float fsub(float a, float b){ return __fsub_rn(a,b); }
__device__ __forceinline__ float fadd(float a, float b){ return __fadd_rn(a,b); }
__device__ __forceinline__ float fmul(float a, float b){ return __fmul_rn(a,b); }

// shfl a u64 across the wave (manual split to avoid overload portability risk)
__device__ __forceinline__ u64 shfl_u64(u64 v, int src) {
    u32 lo = (u32)(v & 0xFFFFFFFFull), hi = (u32)(v >> 32);
    lo = (u32)__shfl((int)lo, src);
    hi = (u32)__shfl((int)hi, src);
    return ((u64)hi << 32) | (u64)lo;
}

// ---------------- Kernel A: score + argmax-class + histogram ----------------
// R5-R9: k_score is at the platform byte-rate floor (~105-110us, FETCH 85.7MB,
// invariant across 5 structurally different implementations). Argmax over
// PRODUCTS fmul(cls,obj) with strict > (first-max-wins); half-combine ties
// favor half 0 == jnp.argmax first-occurrence. conf = max(products) is
// bit-identical to fmul(max(cls),obj) by fmul monotonicity.
__global__ __launch_bounds__(256) void k_score(const float* __restrict__ outp,
                                               float* __restrict__ scores,
                                               u8* __restrict__ clsarr,
                                               u32* __restrict__ hist) {
    __shared__ float srows[SR * ROW];        // 32,640 B -> 4 blocks/CU

    int tid = threadIdx.x;
    size_t base = (size_t)blockIdx.x * SF4;  // float4 index of block chunk
    const float4* src = (const float4*)outp;

    size_t a = base + tid;
    const size_t amax = TOT_F4 - 1;          // clamp only affects last block's tail
    float4 t0 = src[(a            < amax) ? (a           ) : amax];
    float4 t1 = src[(a + 256      < amax) ? (a + 256     ) : amax];
    float4 t2 = src[(a + 512      < amax) ? (a + 512     ) : amax];
    float4 t3 = src[(a + 768      < amax) ? (a + 768     ) : amax];
    float4 t4 = src[(a + 1024     < amax) ? (a + 1024    ) : amax];
    float4 t5 = src[(a + 1280     < amax) ? (a + 1280    ) : amax];
    float4 t6 = src[(a + 1536     < amax) ? (a + 1536    ) : amax];
    float4 t7 = src[(a + 1792     < amax) ? (a + 1792    ) : amax];

    float4* dst = (float4*)srows;
    dst[tid        ] = t0;
    dst[tid +  256 ] = t1;
    dst[tid +  512 ] = t2;
    dst[tid +  768 ] = t3;
    dst[tid + 1024 ] = t4;
    dst[tid + 1280 ] = t5;
    dst[tid + 1536 ] = t6;
    if (tid < SF4 - 1792) dst[tid + 1792] = t7;   // slots 1792..2039
    __syncthreads();

    // compute: 2 lanes per row; each half tracks (best, bi) over 40 products
    int r = tid >> 1;          // row within block [0,96) for tid < 192
    int h = tid & 1;           // half: classes [40h, 40h+40)
    float score = -1.0f;
    int cls = 0;
    int gi = blockIdx.x * SR + r;
    if (tid < 192) {           // waves 0..2 fully active -> shfl_xor(1) safe
        const float* row = srows + r * ROW;
        float obj = row[4];
        const float* cp = row + 5 + h * 40;
        float best = -1.0f; int bi = h * 40;
        #pragma unroll
        for (int c = 0; c < 40; ++c) {
            float v = fmul(cp[c], obj);      // products, reference op
            if (v > best) { best = v; bi = h * 40 + c; }
        }
        float ob  = __shfl_xor(best, 1);
        int   obi = __shfl_xor(bi, 1);
        // from h==0's perspective: other is half 1 -> take only if strictly greater
        float conf;
        if (ob > best) { conf = ob; cls = obi; }
        else           { conf = best; cls = bi; }
        score = (conf > CONF_T) ? conf : -1.0f;
    }

    if (tid < 192 && h == 0) {
        scores[gi] = score;
        clsarr[gi] = (u8)cls;
        if (score > 0.0f) {
            int b = gi / N_ANCH;
            u32 bk = (__float_as_uint(score) >> 16) - KEYBASE;
            if (bk > HBKT - 1) bk = HBKT - 1;   // unreachable for (0.596,1) scores; safety
            atomicAdd(&hist[(size_t)b * HBKT + bk], 1u);
        }
    }
}

// ---------------- Kernel B: find per-image bucket threshold for rank 512 ----------------
__global__ __launch_bounds__(128) void k_thresh(const u32* __restrict__ hist,
                                                u32* __restrict__ thresh) {
    int b = blockIdx.x;
    int tid = threadIdx.x;
    __shared__ u32 h[HBKT];
    h[tid] = hist[(size_t)b * HBKT + tid];
    __syncthreads();
    if (tid == 0) {
        u32 c2 = 0;
        int bkt = HBKT - 1;
        for (; bkt >= 0; --bkt) {
            c2 += h[bkt];
            if (c2 >= MAXC) break;
        }
        thresh[b] = (bkt < 0) ? 0u : (((u32)bkt + KEYBASE) << 16);
    }
}

// ---------------- Kernel C: compact candidates >= threshold ----------------
__global__ __launch_bounds__(256) void k_compact(const float* __restrict__ scores,
                                                 const u32* __restrict__ thresh,
                                                 u32* __restrict__ cnt,
                                                 u64* __restrict__ list) {
    int i = blockIdx.x * blockDim.x + threadIdx.x;
    if (i >= B_IMG * N_ANCH) return;
    float s = scores[i];
    if (s <= 0.0f) return;
    int b = i / N_ANCH;
    u32 key = __float_as_uint(s);
    if (key < thresh[b]) return;
    u32 pos = atomicAdd(&cnt[b], 1u);
    if (pos < CAP) {
        u32 n = (u32)(i - b * N_ANCH);
        // descending sort of packed => key desc, index asc on ties (stable argsort match)
        list[(size_t)b * CAP + pos] = ((u64)key << 32) | (u64)(0xFFFFFFFFu - n);
    }
}

// ---------------- Kernel D1: sort + box extraction (per image) ----------------
// class comes from clsarr (computed in k_score); candidate read is 4 scalar
// floats + 1 byte instead of 85 floats + 80-product argmax.
__global__ __launch_bounds__(512) void k_sort(const float* __restrict__ outp,
                                              const u8* __restrict__ clsarr,
                                              const u32* __restrict__ cnt,
                                              const u64* __restrict__ list,
                                              float* __restrict__ oboxw,
                                              float* __restrict__ areaw,
                                              float* __restrict__ bxw,
                                              u32* __restrict__ nvalidw) {
    __shared__ u64 buf[CAP];
    int b = blockIdx.x;
    int tid = threadIdx.x;

    int M = (int)min(cnt[b], (u32)CAP);
    int P = MAXC;
    while (P < M) P <<= 1;

    for (int t = tid; t < P; t += 512)
        buf[t] = (t < M) ? list[(size_t)b * CAP + t] : 0ull;
    __syncthreads();

    // bitonic sort, descending
    for (int k = 2; k <= P; k <<= 1) {
        for (int j = k >> 1; j > 0; j >>= 1) {
            for (int t = tid; t < P; t += 512) {
                int ixj = t ^ j;
                if (ixj > t) {
                    u64 a = buf[t], c = buf[ixj];
                    bool desc = ((t & k) == 0);
                    if (desc ? (a < c) : (a > c)) { buf[t] = c; buf[ixj] = a; }
                }
            }
            __syncthreads();
        }
    }

    int nvalid = min(M, MAXC);
    bool valid = (tid < nvalid);
    u32 n = 0;
    if (valid) n = 0xFFFFFFFFu - (u32)(buf[tid] & 0xFFFFFFFFull);

    // boxes: replicate reference float ops exactly (no FMA contraction)
    float bx0, bx1, bx2, bx3;
    float ob0, ob1, ob2, ob3;
    if (valid) {
        const float* p = outp + ((size_t)b * N_ANCH + n) * ROW;
        float cx = p[0], cy = p[1], w = p[2], h = p[3];
        int bi = (int)clsarr[(size_t)b * N_ANCH + n];
        float hw = fmul(w, 0.5f), hh = fmul(h, 0.5f);
        bx0 = fsub(cx, hw); bx1 = fsub(cy, hh);
        bx2 = fadd(cx, hw); bx3 = fadd(cy, hh);
        float off = fmul((float)bi, 4096.0f);
        ob0 = fadd(bx0, off); ob1 = fadd(bx1, off);
        ob2 = fadd(bx2, off); ob3 = fadd(bx3, off);
    } else {
        bx0 = bx1 = bx2 = bx3 = 0.0f;
        ob0 = ob1 = ob2 = ob3 = -1.0e6f;  // degenerate far box, iou -> 0
    }
    ((float4*)oboxw)[b * MAXC + tid] = make_float4(ob0, ob1, ob2, ob3);
    areaw[b * MAXC + tid] = fmul(fsub(ob2, ob0), fsub(ob3, ob1));
    ((float4*)bxw)[b * MAXC + tid] = make_float4(bx0, bx1, bx2, bx3);
    if (tid == 0) nvalidw[b] = (u32)nvalid;
}

// ---------------- Kernel D2: IoU bitmatrix, 64x64 tiles, wave-uniform inner loop ----------------
__global__ __launch_bounds__(64) void k_iou(const float* __restrict__ oboxw,
                                            const float* __restrict__ areaw,
                                            u64* __restrict__ sup) {
    int t = blockIdx.x, b = blockIdx.y;
    int ti = 0;
    while (t >= 8 - ti) { t -= 8 - ti; ++ti; }
    int tj = ti + t;

    int lane = threadIdx.x;
    int i = ti * 64 + lane;
    float4 oi = ((const float4*)oboxw)[b * MAXC + i];
    float ai = areaw[b * MAXC + i];

    __shared__ float jb[5][64];
    int jg = tj * 64 + lane;
    float4 oj = ((const float4*)oboxw)[b * MAXC + jg];
    jb[0][lane] = oj.x; jb[1][lane] = oj.y;
    jb[2][lane] = oj.z; jb[3][lane] = oj.w;
    jb[4][lane] = areaw[b * MAXC + jg];
    __syncthreads();

    u64 bits = 0;
    for (int jl = 0; jl < 64; ++jl) {            // jl wave-uniform -> LDS broadcast reads
        int j = tj * 64 + jl;
        float ltx = fmaxf(oi.x, jb[0][jl]);
        float lty = fmaxf(oi.y, jb[1][jl]);
        float rbx = fminf(oi.z, jb[2][jl]);
        float rby = fminf(oi.w, jb[3][jl]);
        float ww = fmaxf(fsub(rbx, ltx), 0.0f);
        float hh2 = fmaxf(fsub(rby, lty), 0.0f);
        float inter = fmul(ww, hh2);
        float denom = fadd(fsub(fadd(ai, jb[4][jl]), inter), 1e-9f);
        float iou = __fdiv_rn(inter, denom);
        if ((j > i) && (iou > IOU_T)) bits |= (1ull << jl);
    }

    u64* sr = sup + ((size_t)(b * MAXC + i)) * 8;
    if (ti == tj) {
        for (int w = 0; w < ti; ++w) sr[w] = 0ull;   // zero lower-tri words of this row
    }
    sr[tj] = bits;
}

// ---------------- Kernel D3: sparse greedy NMS + compaction ----------------
#define GW(W, KW, NE, APPLY) \
    { u64 todo = (KW) & (NE); \
      while (todo) { \
          int bb = (int)__builtin_ctzll(todo); \
          const u64* rr = srow + (((W) * 64 + bb) * 8); \
          u64 hm = (bb < 63) ? (~0ull << (bb + 1)) : 0ull; \
          KW &= ~(rr[W] & hm); \
          APPLY \
          todo &= hm & KW; \
      } }

__global__ __launch_bounds__(512) void k_greedy(const u64* __restrict__ sup,
                                                const u32* __restrict__ nvalidw,
                                                const float* __restrict__ bxw,
                                                float* __restrict__ selbox,
                                                u32* __restrict__ selcnt,
                                                float* __restrict__ mask_out) {
    __shared__ u64 srow[MAXC * 8];   // 32 KB
    __shared__ u64 neword[8];
    __shared__ u64 keepw[8];
    int b = blockIdx.x;
    int tid = threadIdx.x;
    int nvalid = (int)nvalidw[b];

    // stage bitmatrix (coalesced: thread reads 64 consecutive bytes)
    const u64* g = sup + (size_t)b * MAXC * 8;
    u64 r0 = g[tid*8+0], r1 = g[tid*8+1], r2 = g[tid*8+2], r3 = g[tid*8+3];
    u64 r4 = g[tid*8+4], r5 = g[tid*8+5], r6 = g[tid*8+6], r7 = g[tid*8+7];
    srow[tid*8+0]=r0; srow[tid*8+1]=r1; srow[tid*8+2]=r2; srow[tid*8+3]=r3;
    srow[tid*8+4]=r4; srow[tid*8+5]=r5; srow[tid*8+6]=r6; srow[tid*8+7]=r7;
    bool ne = ((r0|r1|r2|r3|r4|r5|r6|r7) != 0ull);
    u64 bal = __ballot(ne);
    if ((tid & 63) == 0) neword[tid >> 6] = bal;
    if (tid < 8) {
        int lo = tid * 64;
        u64 kw = 0;
        if (nvalid >= lo + 64) kw = ~0ull;
        else if (nvalid > lo) kw = (1ull << (nvalid - lo)) - 1ull;
        keepw[tid] = kw;
    }
    __syncthreads();

    if (tid == 0) {
        u64 k0=keepw[0], k1=keepw[1], k2=keepw[2], k3=keepw[3];
        u64 k4=keepw[4], k5=keepw[5], k6=keepw[6], k7=keepw[7];
        u64 n0=neword[0], n1=neword[1], n2=neword[2], n3=neword[3];
        u64 n4=neword[4], n5=neword[5], n6=neword[6], n7=neword[7];
        GW(0, k0, n0, k1&=~rr[1]; k2&=~rr[2]; k3&=~rr[3]; k4&=~rr[4]; k5&=~rr[5]; k6&=~rr[6]; k7&=~rr[7];)
        GW(1, k1, n1, k2&=~rr[2]; k3&=~rr[3]; k4&=~rr[4]; k5&=~rr[5]; k6&=~rr[6]; k7&=~rr[7];)
        GW(2, k2, n2, k3&=~rr[3]; k4&=~rr[4]; k5&=~rr[5]; k6&=~rr[6]; k7&=~rr[7];)
        GW(3, k3, n3, k4&=~rr[4]; k5&=~rr[5]; k6&=~rr[6]; k7&=~rr[7];)
        GW(4, k4, n4, k5&=~rr[5]; k6&=~rr[6]; k7&=~rr[7];)
        GW(5, k5, n5, k6&=~rr[6]; k7&=~rr[7];)
        GW(6, k6, n6, k7&=~rr[7];)
        GW(7, k7, n7, )
        keepw[0]=k0; keepw[1]=k1; keepw[2]=k2; keepw[3]=k3;
        keepw[4]=k4; keepw[5]=k5; keepw[6]=k6; keepw[7]=k7;
    }
    __syncthreads();

    // compact kept in candidate order (== stable top-200 of ks)
    int w = tid >> 6, l = tid & 63;
    bool kept = (tid < nvalid) && ((keepw[w] >> l) & 1ull);
    int rank = 0;
    for (int ww = 0; ww < w; ++ww) rank += __popcll(keepw[ww]);
    rank += __popcll(keepw[w] & ((l == 0) ? 0ull : ((1ull << l) - 1ull)));
    if (kept && rank < CELL) {
        float4 bx = ((const float4*)bxw)[b * MAXC + tid];
        float* sb = selbox + ((size_t)b * CELL + rank) * 4;
        sb[0] = bx.x; sb[1] = bx.y; sb[2] = bx.z; sb[3] = bx.w;
        mask_out[b * CELL + rank] = 1.0f;
    }
    if (tid == 0) {
        int tot = 0;
        for (int ww = 0; ww < 8; ++ww) tot += __popcll(keepw[ww]);
        selcnt[b] = (u32)min(tot, CELL);
    }
}

// ---------------- Fallback fused Kernel D (used only if workspace too small) ----------------
__global__ __launch_bounds__(512) void k_nms(const float* __restrict__ outp,
                                             const u32* __restrict__ cnt,
                                             const u64* __restrict__ list,
                                             float* __restrict__ selbox,
                                             u32* __restrict__ selcnt,
                                             float* __restrict__ mask_out) {
    __shared__ u64 buf[CAP];
    __shared__ float obox[MAXC][4];
    __shared__ float area[MAXC];
    __shared__ u64 keepw[8];
    int b = blockIdx.x;
    int tid = threadIdx.x;

    int M = (int)min(cnt[b], (u32)CAP);
    int P = MAXC;
    while (P < M) P <<= 1;

    for (int t = tid; t < P; t += 512)
        buf[t] = (t < M) ? list[(size_t)b * CAP + t] : 0ull;
    __syncthreads();

    for (int k = 2; k <= P; k <<= 1) {
        for (int j = k >> 1; j > 0; j >>= 1) {
            for (int t = tid; t < P; t += 512) {
                int ixj = t ^ j;
                if (ixj > t) {
                    u64 a = buf[t], c = buf[ixj];
                    bool desc = ((t & k) == 0);
                    if (desc ? (a < c) : (a > c)) { buf[t] = c; buf[ixj] = a; }
                }
            }
            __syncthreads();
        }
    }

    int nvalid = min(M, MAXC);
    bool valid = (tid < nvalid);
    u32 n = 0;
    if (valid) n = 0xFFFFFFFFu - (u32)(buf[tid] & 0xFFFFFFFFull);
    __syncthreads();

    float bx0, bx1, bx2, bx3;
    float ob0, ob1, ob2, ob3;
    if (valid) {
        const float* p = outp + ((size_t)b * N_ANCH + n) * ROW;
        float cx = p[0], cy = p[1], w = p[2], h = p[3], obj = p[4];
        float best = -1.0f; int bi = 0;
        for (int c = 0; c < NCLS; ++c) {
            float v = fmul(p[5 + c], obj);
            if (v > best) { best = v; bi = c; }
        }
        float hw = fmul(w, 0.5f), hh = fmul(h, 0.5f);
        bx0 = fsub(cx, hw); bx1 = fsub(cy, hh);
        bx2 = fadd(cx, hw); bx3 = fadd(cy, hh);
        float off = fmul((float)bi, 4096.0f);
        ob0 = fadd(bx0, off); ob1 = fadd(bx1, off);
        ob2 = fadd(bx2, off); ob3 = fadd(bx3, off);
    } else {
        bx0 = bx1 = bx2 = bx3 = 0.0f;
        ob0 = ob1 = ob2 = ob3 = -1.0e6f;
    }
    obox[tid][0] = ob0; obox[tid][1] = ob1;
    obox[tid][2] = ob2; obox[tid][3] = ob3;
    area[tid] = fmul(fsub(ob2, ob0), fsub(ob3, ob1));
    __syncthreads();

    u64* sup = buf;
    {
        u64 rowb[8] = {0,0,0,0,0,0,0,0};
        float aa = area[tid];
        for (int j = tid + 1; j < MAXC; ++j) {
            float ltx = fmaxf(ob0, obox[j][0]);
            float lty = fmaxf(ob1, obox[j][1]);
            float rbx = fminf(ob2, obox[j][2]);
            float rby = fminf(ob3, obox[j][3]);
            float ww = fmaxf(fsub(rbx, ltx), 0.0f);
            float hh2 = fmaxf(fsub(rby, lty), 0.0f);
            float inter = fmul(ww, hh2);
            float denom = fadd(fsub(fadd(aa, area[j]), inter), 1e-9f);
            float iou = __fdiv_rn(inter, denom);
            if (iou > IOU_T) rowb[j >> 6] |= (1ull << (j & 63));
        }
        for (int w2 = 0; w2 < 8; ++w2) sup[tid * 8 + w2] = rowb[w2];
    }
    __syncthreads();

    if (tid < 64) {
        int lane = tid;
        u64 kw = 0;
        if (lane < 8) {
            int lo = lane * 64;
            if (nvalid >= lo + 64) kw = ~0ull;
            else if (nvalid > lo) kw = (1ull << (nvalid - lo)) - 1ull;
        }
        for (int i = 0; i < MAXC; ++i) {
            u64 wv = shfl_u64(kw, i >> 6);
            if ((wv >> (i & 63)) & 1ull) {
                if (lane < 8) kw &= ~sup[(size_t)i * 8 + lane];
            }
        }
        if (lane < 8) keepw[lane] = kw;
    }
    __syncthreads();

    int w = tid >> 6, l = tid & 63;
    bool kept = valid && ((keepw[w] >> l) & 1ull);
    int rank = 0;
    for (int ww = 0; ww < w; ++ww) rank += __popcll(keepw[ww]);
    rank += __popcll(keepw[w] & ((l == 0) ? 0ull : ((1ull << l) - 1ull)));
    if (kept && rank < CELL) {
        float* sb = selbox + ((size_t)b * CELL + rank) * 4;
        sb[0] = bx0; sb[1] = bx1; sb[2] = bx2; sb[3] = bx3;
        mask_out[b * CELL + rank] = 1.0f;
    }
    if (tid == 0) {
        int tot = 0;
        for (int ww = 0; ww < 8; ++ww) tot += __popcll(keepw[ww]);
        selcnt[b] = (u32)min(tot, CELL);
    }
}

// ---------------- Kernel E1: ROI gather (one thread per channel x sample-point) ----------------
__global__ __launch_bounds__(256) void k_roi_gather(
        const float* __restrict__ x1, const float* __restrict__ x2,
        const float* __restrict__ x3, const float* __restrict__ x4,
        const float* __restrict__ selbox, const u32* __restrict__ selcnt,
        float* __restrict__ rws) {
    int slot = blockIdx.y;
    int b = blockIdx.z;
    if (slot >= (int)selcnt[b]) return;

    int unit = blockIdx.x * 256 + threadIdx.x;   // 0..7679
    int c = unit >> 2;
    int p = unit & 3;

    const float* fb; int Wd; float s; int cl;
    if (c < 128)      { fb = x1 + (size_t)b * 128 * 128 * 128; Wd = 128; s = 0.125f;    cl = c; }
    else if (c < 384) { fb = x2 + (size_t)b * 256 * 64 * 64;   Wd = 64;  s = 0.0625f;   cl = c - 128; }
    else if (c < 896) { fb = x3 + (size_t)b * 512 * 32 * 32;   Wd = 32;  s = 0.03125f;  cl = c - 384; }
    else              { fb = x4 + (size_t)b * 1024 * 16 * 16;  Wd = 16;  s = 0.015625f; cl = c - 896; }

    const float* sb = selbox + ((size_t)b * CELL + slot) * 4;
    float box0 = sb[0], box1 = sb[1], box2 = sb[2], box3 = sb[3];

    float bx1f = box0 * s, by1f = box1 * s;
    float bw = fmaxf(box2 * s - bx1f, 1.0f);
    float bh = fmaxf(box3 * s - by1f, 1.0f);
    float gx = (p & 1)  ? 0.75f : 0.25f;
    float gy = (p >> 1) ? 0.75f : 0.25f;
    float X = bx1f + gx * bw;
    float Y = by1f + gy * bh;
    X = fminf(fmaxf(X, 0.0f), (float)(Wd - 1));
    Y = fminf(fmaxf(Y, 0.0f), (float)(Wd - 1));
    int x0 = (int)floorf(X), y0 = (int)floorf(Y);
    int x1i = min(x0 + 1, Wd - 1), y1i = min(y0 + 1, Wd - 1);
    float wx = X - (float)x0, wy = Y - (float)y0;

    const float* f = fb + (size_t)cl * Wd * Wd;
    float v = f[y0 * Wd + x0]  * ((1.0f - wy) * (1.0f - wx))
            + f[y0 * Wd + x1i] * ((1.0f - wy) * wx)
            + f[y1i * Wd + x0] * (wy * (1.0f - wx))
            + f[y1i * Wd + x1i]* (wy * wx);

    // combine the 4 points in reference order: ((v0+v1)+v2)+v3, then * 0.25
    int lane = threadIdx.x & 63;
    int base = lane & ~3;
    float v0 = __shfl(v, base + 0);
    float v1 = __shfl(v, base + 1);
    float v2 = __shfl(v, base + 2);
    float v3 = __shfl(v, base + 3);
    if (p == 0) {
        rws[((size_t)b * CELL + slot) * 1920 + c] = (((v0 + v1) + v2) + v3) * 0.25f;
    }
}

// ---------------- Kernel E2: 2-layer MLP, 4 slots/block with W1 register reuse ----------------
__global__ __launch_bounds__(256) void k_mlp(
        const float* __restrict__ W1, const float* __restrict__ b1,
        const float* __restrict__ W2, const float* __restrict__ b2,
        const float* __restrict__ selbox, const u32* __restrict__ selcnt,
        const float* __restrict__ rws, float* __restrict__ feats) {
    int slot0 = blockIdx.x * 4;
    int b = blockIdx.y;
    int nsel = (int)selcnt[b];
    if (slot0 >= nsel) return;
    int tid = threadIdx.x;

    __shared__ float psum[4][4][64];   // [slot][part][j]
    __shared__ float h1s[4][64];

    int j = tid & 63, part = tid >> 6;
    const float* r0 = rws + ((size_t)b * CELL + slot0 + 0) * 1920;
    const float* r1 = rws + ((size_t)b * CELL + slot0 + 1) * 1920;
    const float* r2 = rws + ((size_t)b * CELL + slot0 + 2) * 1920;
    const float* r3 = rws + ((size_t)b * CELL + slot0 + 3) * 1920;
    // slots >= nsel read garbage (allocated memory) and are discarded at write.

    {
        float a0 = 0.0f, a1 = 0.0f, a2 = 0.0f, a3 = 0.0f;
        int k0 = part * 480;
        for (int k = k0; k < k0 + 480; ++k) {
            float w = W1[(size_t)k * 64 + j];
            a0 += r0[k] * w;
            a1 += r1[k] * w;
            a2 += r2[k] * w;
            a3 += r3[k] * w;
        }
        psum[0][part][j] = a0;
        psum[1][part][j] = a1;
        psum[2][part][j] = a2;
        psum[3][part][j] = a3;
    }
    __syncthreads();

    int sl = tid >> 6;                 // 4 slots x 64 j across 256 threads
    int slot = slot0 + sl;
    if (slot < nsel) {
        float v = psum[sl][0][j] + psum[sl][1][j] + psum[sl][2][j] + psum[sl][3][j] + b1[j];
        h1s[sl][j] = (v >= 0.0f) ? v : 0.01f * v;
    }
    __syncthreads();

    if (slot < nsel) {
        float acc = b2[j];
        for (int k = 0; k < 64; ++k) acc += h1s[sl][k] * W2[k * 64 + j];
        float v = (acc >= 0.0f) ? acc : 0.01f * acc;
        float* orow = feats + ((size_t)b * CELL + slot) * 68;
        orow[4 + j] = v;
        if (j < 4) {
            const float* sb = selbox + ((size_t)b * CELL + slot) * 4;
            orow[j] = sb[j] * (1.0f / 1024.0f);
        }
    }
}

// ---------------- Fallback: fused ROI align + MLP (used if workspace too small) ----------------
__global__ __launch_bounds__(256) void k_roi_mlp(
        const float* __restrict__ x1, const float* __restrict__ x2,
        const float* __restrict__ x3, const float* __restrict__ x4,
        const float* __restrict__ W1, const float* __restrict__ b1,
        const float* __restrict__ W2, const float* __restrict__ b2,
        const float* __restrict__ selbox, const u32* __restrict__ selcnt,
        float* __restrict__ feats) {
    int slot = blockIdx.x;
    int b = blockIdx.y;
    if (slot >= (int)selcnt[b]) return;
    int tid = threadIdx.x;

    __shared__ float r[1920];
    __shared__ float psum[4][64];
    __shared__ float h1[64];

    const float* sb = selbox + ((size_t)b * CELL + slot) * 4;
    float box0 = sb[0], box1 = sb[1], box2 = sb[2], box3 = sb[3];

    const float* feat[4] = {
        x1 + (size_t)b * 128 * 128 * 128,
        x2 + (size_t)b * 256 * 64 * 64,
        x3 + (size_t)b * 512 * 32 * 32,
        x4 + (size_t)b * 1024 * 16 * 16
    };
    const int   Cs[4]  = {128, 256, 512, 1024};
    const int   Wd_[4] = {128, 64, 32, 16};
    const float Ss[4]  = {0.125f, 0.0625f, 0.03125f, 0.015625f};
    const int   Off[4] = {0, 128, 384, 896};

    for (int lvl = 0; lvl < 4; ++lvl) {
        int Wd = Wd_[lvl], C = Cs[lvl];
        float s = Ss[lvl];
        float bx1f = box0 * s, by1f = box1 * s;
        float bw = fmaxf(box2 * s - bx1f, 1.0f);
        float bh = fmaxf(box3 * s - by1f, 1.0f);
        float xs[2] = { bx1f + 0.25f * bw, bx1f + 0.75f * bw };
        float ys[2] = { by1f + 0.25f * bh, by1f + 0.75f * bh };
        int idx[4][4]; float wt[4][4];
        for (int p = 0; p < 4; ++p) {
            float X = xs[p & 1], Y = ys[p >> 1];
            X = fminf(fmaxf(X, 0.0f), (float)(Wd - 1));
            Y = fminf(fmaxf(Y, 0.0f), (float)(Wd - 1));
            int x0 = (int)floorf(X), y0 = (int)floorf(Y);
            int x1i = min(x0 + 1, Wd - 1), y1i = min(y0 + 1, Wd - 1);
            float wx = X - (float)x0, wy = Y - (float)y0;
            idx[p][0] = y0 * Wd + x0;  idx[p][1] = y0 * Wd + x1i;
            idx[p][2] = y1i * Wd + x0; idx[p][3] = y1i * Wd + x1i;
            wt[p][0] = (1.0f - wy) * (1.0f - wx); wt[p][1] = (1.0f - wy) * wx;
            wt[p][2] = wy * (1.0f - wx);          wt[p][3] = wy * wx;
        }
        const float* fb = feat[lvl];
        int HW = Wd * Wd;
        for (int c = tid; c < C; c += 256) {
            const float* f = fb + (size_t)c * HW;
            float acc = 0.0f;
            for (int p = 0; p < 4; ++p)
                acc += f[idx[p][0]] * wt[p][0] + f[idx[p][1]] * wt[p][1]
                     + f[idx[p][2]] * wt[p][2] + f[idx[p][3]] * wt[p][3];
            r[Off[lvl] + c] = acc * 0.25f;
        }
    }
    __syncthreads();

    int j = tid & 63, part = tid >> 6;
    {
        float acc = 0.0f;
        int k0 = part * 480;
        for (int k = k0; k < k0 + 480; ++k)
            acc += r[k] * W1[(size_t)k * 64 + j];
        psum[part][j] = acc;
    }
    __syncthreads();
    if (tid < 64) {
        float v = psum[0][tid] + psum[1][tid] + psum[2][tid] + psum[3][tid] + b1[tid];
        h1[tid] = (v >= 0.0f) ? v : 0.01f * v;
    }
    __syncthreads();

    float* orow = feats + ((size_t)b * CELL + slot) * 68;
    if (tid < 64) {
        float acc = b2[tid];
        for (int k = 0; k < 64; ++k) acc += h1[k] * W2[k * 64 + tid];
        float v = (acc >= 0.0f) ? acc : 0.01f * acc;
        orow[4 + tid] = v;
    }
    if (tid < 4) {
        float bv = (tid == 0) ? box0 : (tid == 1) ? box1 : (tid == 2) ? box2 : box3;
        orow[tid] = bv * (1.0f / 1024.0f);
    }
}

extern "C" void kernel_launch(void* const* d_in, const int* in_sizes, int n_in,
                              void* d_out, int out_size, void* d_ws, size_t ws_size,
                              hipStream_t stream) {
    const float* outp = (const float*)d_in[0];
    const float* x1 = (const float*)d_in[1];
    const float* x2 = (const float*)d_in[2];
    const float* x3 = (const float*)d_in[3];
    const float* x4 = (const float*)d_in[4];
    const float* W1 = (const float*)d_in[5];
    const float* b1 = (const float*)d_in[6];
    const float* W2 = (const float*)d_in[7];
    const float* b2 = (const float*)d_in[8];

    char* ws = (char*)d_ws;
    const size_t o_cnt    = 0;                       // 256
    const size_t o_hist   = 256;                     // 8*128*4 = 4096
    const size_t o_thresh = 4352;                    // 256
    const size_t o_scores = 4608;                    // 2,064,384
    const size_t o_cls    = o_scores + 2064384;      // 516,096 (u8 per anchor)
    const size_t o_list   = o_cls + 516096;          // 262,144 (8B aligned)
    const size_t o_selbox = o_list + 262144;         // 25,600
    const size_t o_selcnt = o_selbox + 25600;        // 256
    const size_t o_rws    = o_selcnt + 256;          // 12,288,000
    const size_t ws_need_rws = o_rws + (size_t)B_IMG * CELL * 1920 * 4;
    const size_t o_sup    = ws_need_rws;                       // 8*512*8*8 = 262,144
    const size_t o_obox   = o_sup + 262144;                    // 8*512*16 = 65,536
    const size_t o_area   = o_obox + 65536;                    // 8*512*4  = 16,384
    const size_t o_bx     = o_area + 16384;                    // 65,536
    const size_t o_nvalid = o_bx + 65536;                      // 256
    const size_t ws_need_full = o_nvalid + 256;

    u32*   cnt    = (u32*)(ws + o_cnt);
    u32*   hist   = (u32*)(ws + o_hist);
    u32*   thresh = (u32*)(ws + o_thresh);
    float* scores = (float*)(ws + o_scores);
    u8*    clsarr = (u8*)(ws + o_cls);
    u64*   list   = (u64*)(ws + o_list);
    float* selbox = (float*)(ws + o_selbox);
    u32*   selcnt = (u32*)(ws + o_selcnt);
    float* rws    = (float*)(ws + o_rws);
    u64*   sup    = (u64*)(ws + o_sup);
    float* oboxw  = (float*)(ws + o_obox);
    float* areaw  = (float*)(ws + o_area);
    float* bxw    = (float*)(ws + o_bx);
    u32*   nvalidw= (u32*)(ws + o_nvalid);

    float* feats = (float*)d_out;
    float* mask  = feats + (size_t)B_IMG * CELL * 68;

    // zero output (masked rows must be exact 0) and cnt+hist (4.3 KB)
    hipMemsetAsync(d_out, 0, (size_t)out_size * sizeof(float), stream);
    hipMemsetAsync(ws, 0, 4608, stream);

    int total = B_IMG * N_ANCH;
    int blocks = (total + 255) / 256;
    int score_blocks = total / SR;                   // 516096 / 96 = 5376, exact
    k_score  <<<score_blocks, 256, 0, stream>>>(outp, scores, clsarr, hist);
    k_thresh <<<B_IMG, 128, 0, stream>>>(hist, thresh);
    k_compact<<<blocks, 256, 0, stream>>>(scores, thresh, cnt, list);

    if (ws_size >= ws_need_full) {
        k_sort  <<<B_IMG, 512, 0, stream>>>(outp, clsarr, cnt, list, oboxw, areaw, bxw, nvalidw);
        k_iou   <<<dim3(36, B_IMG), 64, 0, stream>>>(oboxw, areaw, sup);
        k_greedy<<<B_IMG, 512, 0, stream>>>(sup, nvalidw, bxw, selbox, selcnt, mask);
    } else {
        k_nms   <<<B_IMG, 512, 0, stream>>>(outp, cnt, list, selbox, selcnt, mask);
    }

    if (ws_size >= ws_need_rws) {
        k_roi_gather<<<dim3(30, CELL, B_IMG), 256, 0, stream>>>(
            x1, x2, x3, x4, selbox, selcnt, rws);
        k_mlp<<<dim3((CELL + 3) / 4, B_IMG), 256, 0, stream>>>(
            W1, b1, W2, b2, selbox, selcnt, rws, feats);
    } else {
        k_roi_mlp<<<dim3(CELL, B_IMG), 256, 0, stream>>>(
            x1, x2, x3, x4, W1, b1, W2, b2, selbox, selcnt, feats);
    }
}